// Round 1
// baseline (18953.172 us; speedup 1.0000x reference)
//
#include <hip/hip_runtime.h>
#include <cmath>

// Problem constants (from setup_inputs): B=64, S=2048, I=512, H=512
#define BB 64
#define SS 2048
#define II 512
#define HH 512

// ---------------------------------------------------------------------------
// Kernel A: xproj[m][n] = sum_k x[m][k] * Wx[n][k] + bh[n]
// M = B*S = 131072, K = I = 512, N = H = 512. All fp32, NT GEMM.
// 64x64 tile, BK=16, 256 threads, 4x4 microtile, LDS stored K-major
// (transposed) so the inner loop uses ds_read_b128.
// ---------------------------------------------------------------------------
__global__ __launch_bounds__(256) void xproj_kernel(
    const float* __restrict__ A,    // x: (M, 512)
    const float* __restrict__ W,    // Wx: (512, 512) row-major (N x K)
    const float* __restrict__ bias, // bh: (512,)
    float* __restrict__ C)          // out: (M, 512)
{
    __shared__ float Ast[16][68];  // [kk][row], pad 68 -> 272B row stride (16B aligned)
    __shared__ float Bst[16][68];

    const int tid = threadIdx.x;
    const long m0 = (long)blockIdx.x * 64;
    const int n0 = blockIdx.y * 64;
    const int row = tid >> 2;          // 0..63
    const int kq = (tid & 3) << 2;     // 0,4,8,12
    const int tx = tid & 15;           // col group
    const int ty = tid >> 4;           // row group

    float acc[4][4] = {};

    for (int k0 = 0; k0 < 512; k0 += 16) {
        float4 a4 = *(const float4*)&A[(m0 + row) * 512 + k0 + kq];
        float4 b4 = *(const float4*)&W[(long)(n0 + row) * 512 + k0 + kq];
        __syncthreads();
        Ast[kq + 0][row] = a4.x; Ast[kq + 1][row] = a4.y;
        Ast[kq + 2][row] = a4.z; Ast[kq + 3][row] = a4.w;
        Bst[kq + 0][row] = b4.x; Bst[kq + 1][row] = b4.y;
        Bst[kq + 2][row] = b4.z; Bst[kq + 3][row] = b4.w;
        __syncthreads();
#pragma unroll
        for (int kk = 0; kk < 16; ++kk) {
            float4 av = *(const float4*)&Ast[kk][ty << 2];
            float4 bv = *(const float4*)&Bst[kk][tx << 2];
            acc[0][0] += av.x * bv.x; acc[0][1] += av.x * bv.y;
            acc[0][2] += av.x * bv.z; acc[0][3] += av.x * bv.w;
            acc[1][0] += av.y * bv.x; acc[1][1] += av.y * bv.y;
            acc[1][2] += av.y * bv.z; acc[1][3] += av.y * bv.w;
            acc[2][0] += av.z * bv.x; acc[2][1] += av.z * bv.y;
            acc[2][2] += av.z * bv.z; acc[2][3] += av.z * bv.w;
            acc[3][0] += av.w * bv.x; acc[3][1] += av.w * bv.y;
            acc[3][2] += av.w * bv.z; acc[3][3] += av.w * bv.w;
        }
    }

    float4 bias4 = *(const float4*)&bias[n0 + (tx << 2)];
#pragma unroll
    for (int a = 0; a < 4; ++a) {
        float4 o;
        o.x = acc[a][0] + bias4.x;
        o.y = acc[a][1] + bias4.y;
        o.z = acc[a][2] + bias4.z;
        o.w = acc[a][3] + bias4.w;
        *(float4*)&C[(m0 + (ty << 2) + a) * 512 + n0 + (tx << 2)] = o;
    }
}

// ---------------------------------------------------------------------------
// Transpose Wh (512x512) -> WhT so recurrence loads are coalesced over j.
// ---------------------------------------------------------------------------
__global__ __launch_bounds__(256) void transpose512(
    const float* __restrict__ in, float* __restrict__ out)
{
    __shared__ float tile[32][33];
    int x = blockIdx.x * 32 + threadIdx.x;
    int y = blockIdx.y * 32 + threadIdx.y;
#pragma unroll
    for (int i = 0; i < 32; i += 8)
        tile[threadIdx.y + i][threadIdx.x] = in[(y + i) * 512 + x];
    __syncthreads();
    x = blockIdx.y * 32 + threadIdx.x;
    y = blockIdx.x * 32 + threadIdx.y;
#pragma unroll
    for (int i = 0; i < 32; i += 8)
        out[(y + i) * 512 + x] = tile[threadIdx.x][threadIdx.y + i];
}

// ---------------------------------------------------------------------------
// Kernel B: sequential recurrence, one block per batch (64 blocks x 512 thr).
// h lives in LDS; out[] already holds xproj+bias and is overwritten in place
// with h_t (read-before-write within the same t). WhT streamed from L2.
//   TRANS=true : Whx = WhT, load Whx[k*512 + j]  (coalesced over j)
//   TRANS=false: Whx = Wh,  load Whx[j*512 + k]  (fallback if ws too small)
// ---------------------------------------------------------------------------
template <bool TRANS>
__global__ __launch_bounds__(512) void rnn_kernel(
    float* __restrict__ out,        // (B, S, H): in = xproj+bias, out = h_t
    const float* __restrict__ Whx,  // (512,512)
    const float* __restrict__ h0,   // (B, H)
    float* __restrict__ hlast)      // (B, H)
{
    __shared__ float h[HH];
    const int b = blockIdx.x;
    const int j = threadIdx.x;

    h[j] = h0[b * HH + j];
    __syncthreads();

    float* po = out + (long)b * SS * HH + j;

    for (int t = 0; t < SS; ++t) {
        float acc = po[(long)t * HH];
#pragma unroll 4
        for (int k = 0; k < HH; k += 4) {
            float4 hv = *(const float4*)&h[k];
            if (TRANS) {
                acc += Whx[(k + 0) * HH + j] * hv.x;
                acc += Whx[(k + 1) * HH + j] * hv.y;
                acc += Whx[(k + 2) * HH + j] * hv.z;
                acc += Whx[(k + 3) * HH + j] * hv.w;
            } else {
                acc += Whx[j * HH + (k + 0)] * hv.x;
                acc += Whx[j * HH + (k + 1)] * hv.y;
                acc += Whx[j * HH + (k + 2)] * hv.z;
                acc += Whx[j * HH + (k + 3)] * hv.w;
            }
        }
        float hn = tanhf(acc);
        __syncthreads();          // all reads of h done
        h[j] = hn;
        po[(long)t * HH] = hn;
        __syncthreads();          // h fully updated before next step
    }

    hlast[b * HH + j] = h[j];
}

extern "C" void kernel_launch(void* const* d_in, const int* in_sizes, int n_in,
                              void* d_out, int out_size, void* d_ws, size_t ws_size,
                              hipStream_t stream) {
    const float* x  = (const float*)d_in[0];  // (B,S,I)
    const float* h0 = (const float*)d_in[1];  // (B,H)
    const float* Wx = (const float*)d_in[2];  // (H,I)
    const float* Wh = (const float*)d_in[3];  // (H,H)
    const float* bh = (const float*)d_in[4];  // (H,)

    float* out = (float*)d_out;               // (B,S,H) then (B,H) h_last
    float* hlast = out + (long)BB * SS * HH;

    // Kernel A: xproj + bias into the outputs region of d_out.
    dim3 gA(BB * SS / 64, HH / 64);
    xproj_kernel<<<gA, 256, 0, stream>>>(x, Wx, bh, out);

    const size_t whBytes = (size_t)HH * HH * sizeof(float);
    if (ws_size >= whBytes) {
        float* WhT = (float*)d_ws;
        transpose512<<<dim3(16, 16), dim3(32, 8), 0, stream>>>(Wh, WhT);
        rnn_kernel<true><<<BB, HH, 0, stream>>>(out, WhT, h0, hlast);
    } else {
        rnn_kernel<false><<<BB, HH, 0, stream>>>(out, Wh, h0, hlast);
    }
}